// Round 7
// baseline (814.945 us; speedup 1.0000x reference)
//
#include <hip/hip_runtime.h>
#include <math.h>

#define BATCH 2048
#define DIN   784
#define HID   512
#define NC    10
#define NS    10

constexpr int HP  = HID + 1;        // 513
constexpr int M2  = NS * BATCH;     // 20480
constexpr int KP2 = 544;            // 513 padded to 17*32
constexpr int KP1 = 800;            // 784 padded to 25*32
constexpr int HROW = 544;           // padded h row length (bf16)
constexpr int PADK = 552;           // LDS B row stride (elems): 552%32=8 -> 2-way only

typedef __attribute__((ext_vector_type(8))) short          short8;
typedef __attribute__((ext_vector_type(8))) unsigned short ushort8;
typedef __attribute__((ext_vector_type(4))) float          floatx4;

__device__ inline unsigned short f2bf(float f) {
    unsigned u = __builtin_bit_cast(unsigned, f);
    u += 0x7FFFu + ((u >> 16) & 1u);
    return (unsigned short)(u >> 16);
}
__device__ inline float bf2f(unsigned short u) {
    return __builtin_bit_cast(float, (unsigned)u << 16);
}

// square each of 8 bf16 lanes; repack via v_perm_b32
__device__ inline short8 sq8(short8 a) {
    union { short8 s; unsigned u[4]; } x;
    x.s = a;
#pragma unroll
    for (int i = 0; i < 4; ++i) {
        unsigned t = x.u[i];
        float lo = __builtin_bit_cast(float, t << 16);
        float hi = __builtin_bit_cast(float, t & 0xFFFF0000u);
        unsigned lq = __builtin_bit_cast(unsigned, lo * lo);
        unsigned hq = __builtin_bit_cast(unsigned, hi * hi);
        x.u[i] = __builtin_amdgcn_perm(hq, lq, 0x07060302u);
    }
    return x.s;
}

#define GLOAD_LDS16(g, l)                                                      \
    __builtin_amdgcn_global_load_lds(                                          \
        (const __attribute__((address_space(1))) void*)(g),                    \
        (__attribute__((address_space(3))) void*)(l), 16, 0, 0)

// ---------------------------------------------------------------------------
// Panel-resident dual GEMM for layers 2/3 (fused activation epilogue).
// One block = one 64-col weight panel (both mats staged once into LDS) x 640
// rows. 512 threads = 8 waves; after the single staging barrier each wave
// independently processes 5 tiles of 16 rows x 64 cols with a fully unrolled
// K-loop (17 ktiles): 1 coalesced-row A load -> sq8 -> 8 ds_read_b128 ->
// 8 MFMA. No barriers in the hot loop -> compiler pipelines A loads with
// rolling vmcnt. eps read directly in epilogue.
// ---------------------------------------------------------------------------
__global__ __launch_bounds__(512)
void dual_gemm_panel(const unsigned short* __restrict__ A,
                     const unsigned short* __restrict__ WTm,
                     const unsigned short* __restrict__ WTs2,
                     const float* __restrict__ eps,
                     unsigned short* __restrict__ hout)
{
    // two 64 x PADK bf16 panels: 2 * 64*552*2 = 141,312 B
    __shared__ __align__(16) char smem[2 * 64 * PADK * 2];
    constexpr int MATB = 64 * PADK * 2;   // 70,656 B per mat

    const int tid  = threadIdx.x;        // 0..511
    const int lane = tid & 63;
    const int w    = tid >> 6;           // wave 0..7
    const int quad = lane >> 4;
    const int l16  = lane & 15;

    const int col0 = blockIdx.x * 64;
    const int rowB = blockIdx.y * 640;

    // ---- stage B panel (both mats) once: coalesced global -> LDS ----
    {
        const unsigned short* gWm = WTm  + (size_t)col0 * KP2;
        const unsigned short* gWs = WTs2 + (size_t)col0 * KP2;
        for (int i = tid; i < 64 * 68; i += 512) {       // 68 16B-chunks per col
            const int col = i / 68, seg = i - col * 68;
            const int go = col * KP2 + seg * 8;
            const int lo = (col * PADK + seg * 8) * 2;
            *(ushort8*)(smem + lo)        = *(const ushort8*)(gWm + go);
            *(ushort8*)(smem + MATB + lo) = *(const ushort8*)(gWs + go);
        }
    }
    __syncthreads();   // the only barrier

    // ---- 5 independent 16-row tiles per wave ----
#pragma unroll 1
    for (int t = 0; t < 5; ++t) {
        const int row0 = rowB + (w * 5 + t) * 16;
        const unsigned short* gA = A + (size_t)(row0 + l16) * HROW + quad * 8;

        floatx4 accm[4] = {};
        floatx4 accs[4] = {};
#pragma unroll
        for (int kt = 0; kt < 17; ++kt) {
            const short8 a = *(const short8*)(gA + kt * 32);
            const short8 q = sq8(a);
#pragma unroll
            for (int j = 0; j < 4; ++j) {
                const int boff = ((j * 16 + l16) * PADK + quad * 8 + kt * 32) * 2;
                const short8 bm = *(const short8*)(smem + boff);
                const short8 bs = *(const short8*)(smem + MATB + boff);
                accm[j] = __builtin_amdgcn_mfma_f32_16x16x32_bf16(a, bm, accm[j], 0, 0, 0);
                accs[j] = __builtin_amdgcn_mfma_f32_16x16x32_bf16(q, bs, accs[j], 0, 0, 0);
            }
        }
        // epilogue: C/D layout col=lane&15, row=quad*4+reg (16-row tile)
#pragma unroll
        for (int j = 0; j < 4; ++j) {
#pragma unroll
            for (int r = 0; r < 4; ++r) {
                const int R = row0 + quad * 4 + r;
                const int C = col0 + j * 16 + l16;
                const float sg = sqrtf(accs[j][r] + 1e-12f);
                float v = accm[j][r] + sg * eps[(size_t)R * HID + C];
                v = v > 0.0f ? v : 0.01f * v;
                hout[(size_t)R * HROW + C] = f2bf(v);
            }
        }
    }
}

// ---------------------------------------------------------------------------
// Layer-1 dual GEMM (r5 structure): block 64x64, 4 waves slice M; B double-
// buffered via global_load_lds; A direct global->VGPR. Writes mu/sg f32.
// ---------------------------------------------------------------------------
__global__ __launch_bounds__(256)
void dual_gemm_l1(const unsigned short* __restrict__ A,
                  const unsigned short* __restrict__ WTm,
                  const unsigned short* __restrict__ WTs2,
                  int Kp,
                  float* __restrict__ mu_out,
                  float* __restrict__ sg_out)
{
    __shared__ __align__(16) char smem[16384];

    const int tid  = threadIdx.x;
    const int lane = tid & 63;
    const int w    = tid >> 6;
    const int quad = lane >> 4;
    const int l16  = lane & 15;

    const int row0 = blockIdx.y * 64;
    const int col0 = blockIdx.x * 64;

    const size_t KpB = (size_t)Kp * 2;
    const char* gBm = (const char*)(WTm  + (size_t)col0 * Kp);
    const char* gBs = (const char*)(WTs2 + (size_t)col0 * Kp);
    const char* gAl = (const char*)(A + (size_t)(row0 + w * 16 + l16) * Kp) + quad * 16;

    const int sr = tid >> 2, ss = tid & 3;
    auto stageB = [&](int kt, char* buf) {
        const size_t go = (size_t)sr * KpB + (size_t)kt * 64 + ss * 16;
        GLOAD_LDS16(gBm + go, buf + tid * 16);
        GLOAD_LDS16(gBs + go, buf + 4096 + tid * 16);
    };

    stageB(0, smem);
    short8 aCur = *(const short8*)(gAl);

    floatx4 accm[4] = {};
    floatx4 accs[4] = {};

    const int ktiles = Kp >> 5;
    for (int kt = 0; kt < ktiles; ++kt) {
        __syncthreads();
        char* cur = smem + (kt & 1) * 8192;
        if (kt + 1 < ktiles) stageB(kt + 1, smem + ((kt + 1) & 1) * 8192);
        const int kNext = (kt + 1 < ktiles) ? kt + 1 : kt;
        short8 aNext = *(const short8*)(gAl + (size_t)kNext * 64);

        const short8 q = sq8(aCur);
#pragma unroll
        for (int j = 0; j < 4; ++j) {
            const int off = ((j * 16 + l16) * 32 + quad * 8) * 2;
            const short8 bm = *(const short8*)(cur + off);
            const short8 bs = *(const short8*)(cur + 4096 + off);
            accm[j] = __builtin_amdgcn_mfma_f32_16x16x32_bf16(aCur, bm, accm[j], 0, 0, 0);
            accs[j] = __builtin_amdgcn_mfma_f32_16x16x32_bf16(q,    bs, accs[j], 0, 0, 0);
        }
        aCur = aNext;
    }

#pragma unroll
    for (int j = 0; j < 4; ++j) {
#pragma unroll
        for (int r = 0; r < 4; ++r) {
            const int rl = w * 16 + quad * 4 + r;
            const int cl = j * 16 + l16;
            const size_t o = (size_t)(row0 + rl) * HID + col0 + cl;
            mu_out[o] = accm[j][r];
            sg_out[o] = sqrtf(accs[j][r] + 1e-12f);
        }
    }
}

// ---------------------------------------------------------------------------
// Weight pack: WTm[n][k] = bf16(Wm[k][n]); WTs2[n][k] = bf16((drop*Ws[k][n])^2)
// ---------------------------------------------------------------------------
__global__ __launch_bounds__(256)
void pack_wT(const float* __restrict__ Wm, const float* __restrict__ Ws,
             const float* __restrict__ dropPtr, int K, int Kp,
             unsigned short* __restrict__ WTm, unsigned short* __restrict__ WTs2)
{
    __shared__ float tm[32][33];
    __shared__ float ts[32][33];
    const float drop = dropPtr[0];
    const int k0 = blockIdx.x * 32, n0 = blockIdx.y * 32;
    const int tx = threadIdx.x, ty = threadIdx.y;   // 32 x 8
#pragma unroll
    for (int i = 0; i < 4; ++i) {
        const int k = k0 + ty + 8 * i;
        float m = 0.0f, s2 = 0.0f;
        if (k < K) {
            m = Wm[(size_t)k * HID + n0 + tx];
            const float s = Ws[(size_t)k * HID + n0 + tx] * drop;
            s2 = s * s;
        }
        tm[ty + 8 * i][tx] = m;
        ts[ty + 8 * i][tx] = s2;
    }
    __syncthreads();
#pragma unroll
    for (int i = 0; i < 4; ++i) {
        const int n = n0 + ty + 8 * i;
        WTm[(size_t)n * Kp + k0 + tx]  = f2bf(tm[tx][ty + 8 * i]);
        WTs2[(size_t)n * Kp + k0 + tx] = f2bf(ts[tx][ty + 8 * i]);
    }
}

// convert inputs f32 [2048 x 784] -> bf16 [2048 x 800] zero-padded
__global__ __launch_bounds__(256)
void convert_x(const float* __restrict__ x, unsigned short* __restrict__ xb)
{
    const int idx = blockIdx.x * 256 + threadIdx.x;   // 2048*100
    if (idx >= BATCH * 100) return;
    const int r = idx / 100;
    const int c8 = (idx - r * 100) * 8;
    ushort8 o;
    if (c8 < DIN) {   // DIN=784=98*8
        const floatx4 a = *(const floatx4*)(x + (size_t)r * DIN + c8);
        const floatx4 b = *(const floatx4*)(x + (size_t)r * DIN + c8 + 4);
#pragma unroll
        for (int j = 0; j < 4; ++j) { o[j] = f2bf(a[j]); o[4 + j] = f2bf(b[j]); }
    } else {
#pragma unroll
        for (int j = 0; j < 8; ++j) o[j] = 0;
    }
    *(ushort8*)(xb + (size_t)r * KP1 + c8) = o;
}

// h1[r][c] = bf16(leaky(mu1[b][c] + sg1[b][c]*eps1[r][c])), full 544-row incl pad
__global__ __launch_bounds__(256)
void expand1(const float* __restrict__ mu1, const float* __restrict__ sg1,
             const float* __restrict__ eps1, unsigned short* __restrict__ h1)
{
    const int idx = blockIdx.x * 256 + threadIdx.x;   // M2*68
    if (idx >= M2 * 68) return;
    const int r  = idx / 68;
    const int c8 = (idx - r * 68) * 8;
    ushort8 o;
    if (c8 < HID) {
        const int b = r & (BATCH - 1);
        const floatx4* ep = (const floatx4*)(eps1 + (size_t)r * HID + c8);
        const floatx4* mp = (const floatx4*)(mu1 + (size_t)b * HID + c8);
        const floatx4* sp = (const floatx4*)(sg1 + (size_t)b * HID + c8);
        const floatx4 e0 = ep[0], e1 = ep[1];
        const floatx4 m0 = mp[0], m1 = mp[1];
        const floatx4 s0 = sp[0], s1 = sp[1];
#pragma unroll
        for (int j = 0; j < 4; ++j) {
            float v = m0[j] + s0[j] * e0[j];
            v = v > 0.0f ? v : 0.01f * v;
            o[j] = f2bf(v);
            float u = m1[j] + s1[j] * e1[j];
            u = u > 0.0f ? u : 0.01f * u;
            o[4 + j] = f2bf(u);
        }
    } else {
#pragma unroll
        for (int j = 0; j < 8; ++j) o[j] = 0;
        if (c8 == HID) o[0] = 0x3F80;   // bf16(1.0) ones column
    }
    *(ushort8*)(h1 + (size_t)r * HROW + c8) = o;
}

// pad columns 512..543 of an h buffer (ones col + zeros)
__global__ __launch_bounds__(256)
void pad_h(unsigned short* __restrict__ h)
{
    const int idx = blockIdx.x * 256 + threadIdx.x;   // M2*4
    if (idx >= M2 * 4) return;
    const int r = idx >> 2, seg = idx & 3;
    ushort8 o;
#pragma unroll
    for (int j = 0; j < 8; ++j) o[j] = 0;
    if (seg == 0) o[0] = 0x3F80;
    *(ushort8*)(h + (size_t)r * HROW + HID + seg * 8) = o;
}

// Layer 4: per-wave dot products (N=10) + fused log_softmax; h3 is bf16 [M2 x 544]
__global__ __launch_bounds__(256)
void layer4(const unsigned short* __restrict__ h3, const float* __restrict__ Wm,
            const float* __restrict__ Ws, const float* __restrict__ eps4,
            float* __restrict__ out)
{
    const int wave = (int)((blockIdx.x * 256 + threadIdx.x) >> 6);
    const int lane = threadIdx.x & 63;
    if (wave >= M2) return;

    const unsigned short* x = h3 + (size_t)wave * HROW;
    float am[NC] = {}, as[NC] = {};
    for (int k = lane; k < HP; k += 64) {
        const float xv = bf2f(x[k]);
        const float xs = xv * xv;
#pragma unroll
        for (int c = 0; c < NC; ++c) {
            am[c] = fmaf(xv, Wm[k * NC + c], am[c]);
            const float s = Ws[k * NC + c];
            as[c] = fmaf(xs, s * s, as[c]);
        }
    }
#pragma unroll
    for (int off = 32; off; off >>= 1) {
#pragma unroll
        for (int c = 0; c < NC; ++c) {
            am[c] += __shfl_xor(am[c], off, 64);
            as[c] += __shfl_xor(as[c], off, 64);
        }
    }
    if (lane == 0) {
        float logit[NC];
        float mx = -1e30f;
#pragma unroll
        for (int c = 0; c < NC; ++c) {
            const float sg = sqrtf(as[c] + 1e-12f);
            logit[c] = am[c] + sg * eps4[(size_t)wave * NC + c];
            mx = fmaxf(mx, logit[c]);
        }
        float sum = 0.0f;
#pragma unroll
        for (int c = 0; c < NC; ++c) sum += expf(logit[c] - mx);
        const float lse = mx + logf(sum);
#pragma unroll
        for (int c = 0; c < NC; ++c) out[(size_t)wave * NC + c] = logit[c] - lse;
    }
}

// ---------------------------------------------------------------------------
extern "C" void kernel_launch(void* const* d_in, const int* in_sizes, int n_in,
                              void* d_out, int out_size, void* d_ws, size_t ws_size,
                              hipStream_t stream)
{
    const float* inputs   = (const float*)d_in[0];
    const float* a1_mean  = (const float*)d_in[1];
    const float* a1_scale = (const float*)d_in[2];
    const float* a1_drop  = (const float*)d_in[3];
    const float* a2_mean  = (const float*)d_in[4];
    const float* a2_scale = (const float*)d_in[5];
    const float* a2_drop  = (const float*)d_in[6];
    const float* a3_mean  = (const float*)d_in[7];
    const float* a3_scale = (const float*)d_in[8];
    const float* a3_drop  = (const float*)d_in[9];
    const float* a4_mean  = (const float*)d_in[10];
    const float* a4_scale = (const float*)d_in[11];
    const float* eps1     = (const float*)d_in[12];
    const float* eps2     = (const float*)d_in[13];
    const float* eps3     = (const float*)d_in[14];
    const float* eps4     = (const float*)d_in[15];
    float* out = (float*)d_out;

    char* p = (char*)d_ws;
    unsigned short* h_a  = (unsigned short*)p; p += (size_t)M2 * HROW * 2;
    unsigned short* h_b  = (unsigned short*)p; p += (size_t)M2 * HROW * 2;
    unsigned short* xb   = (unsigned short*)p; p += (size_t)BATCH * KP1 * 2;
    unsigned short* WT1m = (unsigned short*)p; p += (size_t)HID * KP1 * 2;
    unsigned short* WT1s = (unsigned short*)p; p += (size_t)HID * KP1 * 2;
    unsigned short* WT2m = (unsigned short*)p; p += (size_t)HID * KP2 * 2;
    unsigned short* WT2s = (unsigned short*)p; p += (size_t)HID * KP2 * 2;
    unsigned short* WT3m = (unsigned short*)p; p += (size_t)HID * KP2 * 2;
    unsigned short* WT3s = (unsigned short*)p; p += (size_t)HID * KP2 * 2;
    float* mu1 = (float*)p; p += (size_t)BATCH * HID * 4;
    float* sg1 = (float*)p; p += (size_t)BATCH * HID * 4;

    // pack / convert
    convert_x<<<(BATCH * 100 + 255) / 256, 256, 0, stream>>>(inputs, xb);
    pack_wT<<<dim3(KP1 / 32, HID / 32), dim3(32, 8), 0, stream>>>(a1_mean, a1_scale, a1_drop, DIN, KP1, WT1m, WT1s);
    pack_wT<<<dim3(KP2 / 32, HID / 32), dim3(32, 8), 0, stream>>>(a2_mean, a2_scale, a2_drop, HP, KP2, WT2m, WT2s);
    pack_wT<<<dim3(KP2 / 32, HID / 32), dim3(32, 8), 0, stream>>>(a3_mean, a3_scale, a3_drop, HP, KP2, WT3m, WT3s);
    pad_h<<<(M2 * 4 + 255) / 256, 256, 0, stream>>>(h_b);

    // layer 1 (sample-shared): mu1/sg1 [2048 x 512]
    dual_gemm_l1<<<dim3(HID / 64, BATCH / 64), 256, 0, stream>>>(
        xb, WT1m, WT1s, KP1, mu1, sg1);

    // expand to h1 [20480 x 544] (incl ones + zero pad)
    expand1<<<(M2 * 68 + 255) / 256, 256, 0, stream>>>(mu1, sg1, eps1, h_a);

    // layer 2 fused -> h_b  (8 col panels x 32 row groups = 256 blocks)
    dual_gemm_panel<<<dim3(HID / 64, M2 / 640), 512, 0, stream>>>(
        h_a, WT2m, WT2s, eps2, h_b);

    // layer 3 fused -> h_a (pad cols survive from expand1)
    dual_gemm_panel<<<dim3(HID / 64, M2 / 640), 512, 0, stream>>>(
        h_b, WT3m, WT3s, eps3, h_a);

    // layer 4 + log_softmax
    layer4<<<(M2 * 64 + 255) / 256, 256, 0, stream>>>(h_a, a4_mean, a4_scale, eps4, out);
}

// Round 8
// 383.193 us; speedup vs baseline: 2.1267x; 2.1267x over previous
//
#include <hip/hip_runtime.h>
#include <math.h>

#define BATCH 2048
#define DIN   784
#define HID   512
#define NC    10
#define NS    10

constexpr int HP  = HID + 1;        // 513
constexpr int M2  = NS * BATCH;     // 20480
constexpr int KP2 = 544;            // 513 padded to 17*32
constexpr int KP1 = 800;            // 784 padded to 25*32
constexpr int HROW = 544;           // padded h row length (bf16)

typedef __attribute__((ext_vector_type(8))) short          short8;
typedef __attribute__((ext_vector_type(8))) unsigned short ushort8;
typedef __attribute__((ext_vector_type(4))) float          floatx4;

__device__ inline unsigned short f2bf(float f) {
    unsigned u = __builtin_bit_cast(unsigned, f);
    u += 0x7FFFu + ((u >> 16) & 1u);
    return (unsigned short)(u >> 16);
}
__device__ inline float bf2f(unsigned short u) {
    return __builtin_bit_cast(float, (unsigned)u << 16);
}

// square each of 8 bf16 lanes; repack via v_perm_b32
__device__ inline short8 sq8(short8 a) {
    union { short8 s; unsigned u[4]; } x;
    x.s = a;
#pragma unroll
    for (int i = 0; i < 4; ++i) {
        unsigned t = x.u[i];
        float lo = __builtin_bit_cast(float, t << 16);
        float hi = __builtin_bit_cast(float, t & 0xFFFF0000u);
        unsigned lq = __builtin_bit_cast(unsigned, lo * lo);
        unsigned hq = __builtin_bit_cast(unsigned, hi * hi);
        x.u[i] = __builtin_amdgcn_perm(hq, lq, 0x07060302u);
    }
    return x.s;
}

#define GLOAD_LDS16(g, l)                                                      \
    __builtin_amdgcn_global_load_lds(                                          \
        (const __attribute__((address_space(1))) void*)(g),                    \
        (__attribute__((address_space(3))) void*)(l), 16, 0, 0)

// ---------------------------------------------------------------------------
// Dual MFMA GEMM (r5 structure, occupancy-tuned): accm = A@Wm, accs=(A²)@Ws2.
// Block 64x64, 4 waves sliced in M (each wave: 16 rows x 64 cols -> sq8 once).
// B (both mats) double-buffered in 16 KB LDS via global_load_lds -> 8 blocks/CU
// (wave-limited, max occupancy). A loaded direct global->VGPR one ktile ahead
// (coalesced at line granularity: 4 quads cover one 64B line per row).
// eps (16 f32/thread) prefetched into VGPRs BEFORE the K-loop -- lands during
// early ktiles, so the epilogue has no exposed load tail.
// ---------------------------------------------------------------------------
__global__ __launch_bounds__(256)
void dual_gemm_mfma(const unsigned short* __restrict__ A,
                    const unsigned short* __restrict__ WTm,
                    const unsigned short* __restrict__ WTs2,
                    int Kp,
                    const float* __restrict__ eps,
                    unsigned short* __restrict__ hout,
                    float* __restrict__ mu_out,
                    float* __restrict__ sg_out)
{
    __shared__ __align__(16) char smem[16384];   // B dbuf only

    const int tid  = threadIdx.x;
    const int lane = tid & 63;
    const int w    = tid >> 6;
    const int quad = lane >> 4;
    const int l16  = lane & 15;

    const int row0 = blockIdx.y * 64;
    const int col0 = blockIdx.x * 64;

    const size_t KpB = (size_t)Kp * 2;
    const char* gBm = (const char*)(WTm  + (size_t)col0 * Kp);
    const char* gBs = (const char*)(WTs2 + (size_t)col0 * Kp);
    const char* gAl = (const char*)(A + (size_t)(row0 + w * 16 + l16) * Kp) + quad * 16;

    // ---- eps prefetch into VGPRs (independent, coalesced) ----
    float epr[4][4];
    if (eps != nullptr) {
        const float* gE = eps + (size_t)(row0 + w * 16 + quad * 4) * HID + col0 + l16;
#pragma unroll
        for (int j = 0; j < 4; ++j)
#pragma unroll
            for (int r = 0; r < 4; ++r)
                epr[j][r] = gE[(size_t)r * HID + j * 16];
    }

    const int sr = tid >> 2, ss = tid & 3;
    auto stageB = [&](int kt, char* buf) {
        const size_t go = (size_t)sr * KpB + (size_t)kt * 64 + ss * 16;
        GLOAD_LDS16(gBm + go, buf + tid * 16);
        GLOAD_LDS16(gBs + go, buf + 4096 + tid * 16);
    };

    stageB(0, smem);
    short8 aCur = *(const short8*)(gAl);

    floatx4 accm[4] = {};
    floatx4 accs[4] = {};

    const int ktiles = Kp >> 5;
    for (int kt = 0; kt < ktiles; ++kt) {
        __syncthreads();   // drains B(kt) + aCur (issued last iter, overlapped)
        char* cur = smem + (kt & 1) * 8192;
        if (kt + 1 < ktiles) stageB(kt + 1, smem + ((kt + 1) & 1) * 8192);
        const int kNext = (kt + 1 < ktiles) ? kt + 1 : kt;
        short8 aNext = *(const short8*)(gAl + (size_t)kNext * 64);

        const short8 q = sq8(aCur);
#pragma unroll
        for (int j = 0; j < 4; ++j) {
            const int off = ((j * 16 + l16) * 32 + quad * 8) * 2;
            const short8 bm = *(const short8*)(cur + off);
            const short8 bs = *(const short8*)(cur + 4096 + off);
            accm[j] = __builtin_amdgcn_mfma_f32_16x16x32_bf16(aCur, bm, accm[j], 0, 0, 0);
            accs[j] = __builtin_amdgcn_mfma_f32_16x16x32_bf16(q,    bs, accs[j], 0, 0, 0);
        }
        aCur = aNext;
    }

    // epilogue: C/D layout col=lane&15, row=quad*4+reg; wave w owns 16 rows
    if (eps != nullptr) {
#pragma unroll
        for (int j = 0; j < 4; ++j) {
#pragma unroll
            for (int r = 0; r < 4; ++r) {
                const int rl = w * 16 + quad * 4 + r;
                const int cl = j * 16 + l16;
                const float sg = sqrtf(accs[j][r] + 1e-12f);
                float v = accm[j][r] + sg * epr[j][r];
                v = v > 0.0f ? v : 0.01f * v;
                hout[(size_t)(row0 + rl) * HROW + col0 + cl] = f2bf(v);
            }
        }
    } else {
#pragma unroll
        for (int j = 0; j < 4; ++j) {
#pragma unroll
            for (int r = 0; r < 4; ++r) {
                const int rl = w * 16 + quad * 4 + r;
                const int cl = j * 16 + l16;
                const size_t o = (size_t)(row0 + rl) * HID + col0 + cl;
                mu_out[o] = accm[j][r];
                sg_out[o] = sqrtf(accs[j][r] + 1e-12f);
            }
        }
    }
}

// ---------------------------------------------------------------------------
// Weight pack: WTm[n][k] = bf16(Wm[k][n]); WTs2[n][k] = bf16((drop*Ws[k][n])^2)
// ---------------------------------------------------------------------------
__global__ __launch_bounds__(256)
void pack_wT(const float* __restrict__ Wm, const float* __restrict__ Ws,
             const float* __restrict__ dropPtr, int K, int Kp,
             unsigned short* __restrict__ WTm, unsigned short* __restrict__ WTs2)
{
    __shared__ float tm[32][33];
    __shared__ float ts[32][33];
    const float drop = dropPtr[0];
    const int k0 = blockIdx.x * 32, n0 = blockIdx.y * 32;
    const int tx = threadIdx.x, ty = threadIdx.y;   // 32 x 8
#pragma unroll
    for (int i = 0; i < 4; ++i) {
        const int k = k0 + ty + 8 * i;
        float m = 0.0f, s2 = 0.0f;
        if (k < K) {
            m = Wm[(size_t)k * HID + n0 + tx];
            const float s = Ws[(size_t)k * HID + n0 + tx] * drop;
            s2 = s * s;
        }
        tm[ty + 8 * i][tx] = m;
        ts[ty + 8 * i][tx] = s2;
    }
    __syncthreads();
#pragma unroll
    for (int i = 0; i < 4; ++i) {
        const int n = n0 + ty + 8 * i;
        WTm[(size_t)n * Kp + k0 + tx]  = f2bf(tm[tx][ty + 8 * i]);
        WTs2[(size_t)n * Kp + k0 + tx] = f2bf(ts[tx][ty + 8 * i]);
    }
}

// convert inputs f32 [2048 x 784] -> bf16 [2048 x 800] zero-padded
__global__ __launch_bounds__(256)
void convert_x(const float* __restrict__ x, unsigned short* __restrict__ xb)
{
    const int idx = blockIdx.x * 256 + threadIdx.x;   // 2048*100
    if (idx >= BATCH * 100) return;
    const int r = idx / 100;
    const int c8 = (idx - r * 100) * 8;
    ushort8 o;
    if (c8 < DIN) {   // DIN=784=98*8
        const floatx4 a = *(const floatx4*)(x + (size_t)r * DIN + c8);
        const floatx4 b = *(const floatx4*)(x + (size_t)r * DIN + c8 + 4);
#pragma unroll
        for (int j = 0; j < 4; ++j) { o[j] = f2bf(a[j]); o[4 + j] = f2bf(b[j]); }
    } else {
#pragma unroll
        for (int j = 0; j < 8; ++j) o[j] = 0;
    }
    *(ushort8*)(xb + (size_t)r * KP1 + c8) = o;
}

// h1[r][c] = bf16(leaky(mu1[b][c] + sg1[b][c]*eps1[r][c])), full 544-row incl pad
__global__ __launch_bounds__(256)
void expand1(const float* __restrict__ mu1, const float* __restrict__ sg1,
             const float* __restrict__ eps1, unsigned short* __restrict__ h1)
{
    const int idx = blockIdx.x * 256 + threadIdx.x;   // M2*68
    if (idx >= M2 * 68) return;
    const int r  = idx / 68;
    const int c8 = (idx - r * 68) * 8;
    ushort8 o;
    if (c8 < HID) {
        const int b = r & (BATCH - 1);
        const floatx4* ep = (const floatx4*)(eps1 + (size_t)r * HID + c8);
        const floatx4* mp = (const floatx4*)(mu1 + (size_t)b * HID + c8);
        const floatx4* sp = (const floatx4*)(sg1 + (size_t)b * HID + c8);
        const floatx4 e0 = ep[0], e1 = ep[1];
        const floatx4 m0 = mp[0], m1 = mp[1];
        const floatx4 s0 = sp[0], s1 = sp[1];
#pragma unroll
        for (int j = 0; j < 4; ++j) {
            float v = m0[j] + s0[j] * e0[j];
            v = v > 0.0f ? v : 0.01f * v;
            o[j] = f2bf(v);
            float u = m1[j] + s1[j] * e1[j];
            u = u > 0.0f ? u : 0.01f * u;
            o[4 + j] = f2bf(u);
        }
    } else {
#pragma unroll
        for (int j = 0; j < 8; ++j) o[j] = 0;
        if (c8 == HID) o[0] = 0x3F80;   // bf16(1.0) ones column
    }
    *(ushort8*)(h1 + (size_t)r * HROW + c8) = o;
}

// pad columns 512..543 of an h buffer (ones col + zeros)
__global__ __launch_bounds__(256)
void pad_h(unsigned short* __restrict__ h)
{
    const int idx = blockIdx.x * 256 + threadIdx.x;   // M2*4
    if (idx >= M2 * 4) return;
    const int r = idx >> 2, seg = idx & 3;
    ushort8 o;
#pragma unroll
    for (int j = 0; j < 8; ++j) o[j] = 0;
    if (seg == 0) o[0] = 0x3F80;
    *(ushort8*)(h + (size_t)r * HROW + HID + seg * 8) = o;
}

// Layer 4: per-wave dot products (N=10) + fused log_softmax; h3 is bf16 [M2 x 544]
__global__ __launch_bounds__(256)
void layer4(const unsigned short* __restrict__ h3, const float* __restrict__ Wm,
            const float* __restrict__ Ws, const float* __restrict__ eps4,
            float* __restrict__ out)
{
    const int wave = (int)((blockIdx.x * 256 + threadIdx.x) >> 6);
    const int lane = threadIdx.x & 63;
    if (wave >= M2) return;

    const unsigned short* x = h3 + (size_t)wave * HROW;
    float am[NC] = {}, as[NC] = {};
    for (int k = lane; k < HP; k += 64) {
        const float xv = bf2f(x[k]);
        const float xs = xv * xv;
#pragma unroll
        for (int c = 0; c < NC; ++c) {
            am[c] = fmaf(xv, Wm[k * NC + c], am[c]);
            const float s = Ws[k * NC + c];
            as[c] = fmaf(xs, s * s, as[c]);
        }
    }
#pragma unroll
    for (int off = 32; off; off >>= 1) {
#pragma unroll
        for (int c = 0; c < NC; ++c) {
            am[c] += __shfl_xor(am[c], off, 64);
            as[c] += __shfl_xor(as[c], off, 64);
        }
    }
    if (lane == 0) {
        float logit[NC];
        float mx = -1e30f;
#pragma unroll
        for (int c = 0; c < NC; ++c) {
            const float sg = sqrtf(as[c] + 1e-12f);
            logit[c] = am[c] + sg * eps4[(size_t)wave * NC + c];
            mx = fmaxf(mx, logit[c]);
        }
        float sum = 0.0f;
#pragma unroll
        for (int c = 0; c < NC; ++c) sum += expf(logit[c] - mx);
        const float lse = mx + logf(sum);
#pragma unroll
        for (int c = 0; c < NC; ++c) out[(size_t)wave * NC + c] = logit[c] - lse;
    }
}

// ---------------------------------------------------------------------------
extern "C" void kernel_launch(void* const* d_in, const int* in_sizes, int n_in,
                              void* d_out, int out_size, void* d_ws, size_t ws_size,
                              hipStream_t stream)
{
    const float* inputs   = (const float*)d_in[0];
    const float* a1_mean  = (const float*)d_in[1];
    const float* a1_scale = (const float*)d_in[2];
    const float* a1_drop  = (const float*)d_in[3];
    const float* a2_mean  = (const float*)d_in[4];
    const float* a2_scale = (const float*)d_in[5];
    const float* a2_drop  = (const float*)d_in[6];
    const float* a3_mean  = (const float*)d_in[7];
    const float* a3_scale = (const float*)d_in[8];
    const float* a3_drop  = (const float*)d_in[9];
    const float* a4_mean  = (const float*)d_in[10];
    const float* a4_scale = (const float*)d_in[11];
    const float* eps1     = (const float*)d_in[12];
    const float* eps2     = (const float*)d_in[13];
    const float* eps3     = (const float*)d_in[14];
    const float* eps4     = (const float*)d_in[15];
    float* out = (float*)d_out;

    char* p = (char*)d_ws;
    unsigned short* h_a  = (unsigned short*)p; p += (size_t)M2 * HROW * 2;
    unsigned short* h_b  = (unsigned short*)p; p += (size_t)M2 * HROW * 2;
    unsigned short* xb   = (unsigned short*)p; p += (size_t)BATCH * KP1 * 2;
    unsigned short* WT1m = (unsigned short*)p; p += (size_t)HID * KP1 * 2;
    unsigned short* WT1s = (unsigned short*)p; p += (size_t)HID * KP1 * 2;
    unsigned short* WT2m = (unsigned short*)p; p += (size_t)HID * KP2 * 2;
    unsigned short* WT2s = (unsigned short*)p; p += (size_t)HID * KP2 * 2;
    unsigned short* WT3m = (unsigned short*)p; p += (size_t)HID * KP2 * 2;
    unsigned short* WT3s = (unsigned short*)p; p += (size_t)HID * KP2 * 2;
    float* mu1 = (float*)p; p += (size_t)BATCH * HID * 4;
    float* sg1 = (float*)p; p += (size_t)BATCH * HID * 4;

    // pack / convert
    convert_x<<<(BATCH * 100 + 255) / 256, 256, 0, stream>>>(inputs, xb);
    pack_wT<<<dim3(KP1 / 32, HID / 32), dim3(32, 8), 0, stream>>>(a1_mean, a1_scale, a1_drop, DIN, KP1, WT1m, WT1s);
    pack_wT<<<dim3(KP2 / 32, HID / 32), dim3(32, 8), 0, stream>>>(a2_mean, a2_scale, a2_drop, HP, KP2, WT2m, WT2s);
    pack_wT<<<dim3(KP2 / 32, HID / 32), dim3(32, 8), 0, stream>>>(a3_mean, a3_scale, a3_drop, HP, KP2, WT3m, WT3s);
    pad_h<<<(M2 * 4 + 255) / 256, 256, 0, stream>>>(h_b);

    // layer 1 (sample-shared): mu1/sg1 [2048 x 512]
    dual_gemm_mfma<<<dim3(HID / 64, BATCH / 64), 256, 0, stream>>>(
        xb, WT1m, WT1s, KP1, nullptr, nullptr, mu1, sg1);

    // expand to h1 [20480 x 544] (incl ones + zero pad)
    expand1<<<(M2 * 68 + 255) / 256, 256, 0, stream>>>(mu1, sg1, eps1, h_a);

    // layer 2 fused -> h_b
    dual_gemm_mfma<<<dim3(HID / 64, M2 / 64), 256, 0, stream>>>(
        h_a, WT2m, WT2s, KP2, eps2, h_b, nullptr, nullptr);

    // layer 3 fused -> h_a (pad cols survive from expand1)
    dual_gemm_mfma<<<dim3(HID / 64, M2 / 64), 256, 0, stream>>>(
        h_b, WT3m, WT3s, KP2, eps3, h_a, nullptr, nullptr);

    // layer 4 + log_softmax
    layer4<<<(M2 * 64 + 255) / 256, 256, 0, stream>>>(h_a, a4_mean, a4_scale, eps4, out);
}